// Round 5
// baseline (312.076 us; speedup 1.0000x reference)
//
#include <hip/hip_runtime.h>

#define B_ 32
#define CD 128
#define O3 384
#define N  4096
#define H_ 4
#define C_ 32

typedef __bf16 bf16x8 __attribute__((ext_vector_type(8)));
typedef float floatx4 __attribute__((ext_vector_type(4)));

#define MFMA16(a, b, c) __builtin_amdgcn_mfma_f32_16x16x32_bf16(a, b, c, 0, 0, 0)

__device__ __forceinline__ float b2f(unsigned int u) {   // low 16 bits
  return __builtin_bit_cast(float, u << 16);
}
__device__ __forceinline__ float b2fh(unsigned int u) {  // high 16 bits
  return __builtin_bit_cast(float, u & 0xffff0000u);
}
__device__ __forceinline__ unsigned short f2b(float f) {
  unsigned int bits = __builtin_bit_cast(unsigned int, f);
  unsigned int r = (bits + 0x7FFFu + ((bits >> 16) & 1u)) >> 16;
  return (unsigned short)r;
}

// ---------------------------------------------------------------------------
// K0: transpose+convert x [b][c][n] fp32 -> xT [b][n][c] bf16, PLUS (on 66
// blocks of the z==0,y<2 plane) the weight conversions formerly in k0_w,
// plus counter zeroing (wid==66). Node count 6 -> 4 total.
// ---------------------------------------------------------------------------
__global__ __launch_bounds__(256) void k0_xt(
    const float* __restrict__ x, unsigned short* __restrict__ xT,
    const float* __restrict__ qkv_w, const float* __restrict__ proj_w,
    const float* __restrict__ dw_w, const float* __restrict__ dw_b,
    unsigned short* __restrict__ qkv_wb, unsigned short* __restrict__ proj_wb,
    float4* __restrict__ dwq, unsigned int* __restrict__ cnt)
{
  __shared__ float xt[32 * 68];
  const int t = threadIdx.x;
  const int n0 = blockIdx.x * 64, c0 = blockIdx.y * 32, b = blockIdx.z;
  const float* xb = x + ((size_t)b * CD + c0) * N + n0;
#pragma unroll
  for (int i = 0; i < 2; i++) {
    int f = i * 256 + t;
    int c = f >> 4, n4 = (f & 15) * 4;
    float4 v = *(const float4*)(xb + (size_t)c * N + n4);
    *(float4*)&xt[c * 68 + n4] = v;
  }

  // ---- weight-conversion side work (66 blocks) + counter zeroing ----
  if (blockIdx.z == 0 && blockIdx.y < 2) {
    int wid = blockIdx.y * 64 + blockIdx.x;
    if (wid < 66) {
      int e = (wid * 256 + t) * 4;
      if (e < 49152) {
        float4 v = *(const float4*)(qkv_w + e);
        unsigned short tmp[4] = {f2b(v.x), f2b(v.y), f2b(v.z), f2b(v.w)};
        *(uint2*)(qkv_wb + e) = *(uint2*)tmp;
      } else if (e < 65536) {
        int off = e - 49152;
        float4 v = *(const float4*)(proj_w + off);
        unsigned short tmp[4] = {f2b(v.x), f2b(v.y), f2b(v.z), f2b(v.w)};
        *(uint2*)(proj_wb + off) = *(uint2*)tmp;
      } else {
        int o = (e - 65536) >> 2;
        if (o < 384)
          dwq[o] = make_float4(dw_w[o * 9 + 1], dw_w[o * 9 + 4],
                               dw_w[o * 9 + 7], dw_b[o]);
      }
    } else if (wid == 66 && t < 32) {
      cnt[t] = 0u;          // per-batch completion counters (live in d_out)
    }
  }

  __syncthreads();
  int n = t >> 2, cb = (t & 3) * 8;
  unsigned short tmp[8];
#pragma unroll
  for (int j = 0; j < 8; j++) tmp[j] = f2b(xt[(cb + j) * 68 + n]);
  *(uint4*)(xT + ((size_t)b * N + n0 + n) * CD + c0 + cb) = *(uint4*)tmp;
}

// ---------------------------------------------------------------------------
// K1: MFMA GEMM (128o x 124y outputs, 128 staged rows incl. 2+2 halo, K=128)
// + bias + 3-tap depthwise + bias. Proven round-3 structure plus:
//  - interior/edge specialization of both pres scatter phases
//  - v-path sweep processes o-PAIRS: dword LDS reads + dword vT stores
// grid (3, 34, 32) otile-fastest. LDS 34,816 B -> 4 blocks/CU.
// ---------------------------------------------------------------------------
__global__ __launch_bounds__(256, 4) void k1_qkv_dw(
    const unsigned short* __restrict__ xT, const unsigned short* __restrict__ qkv_wb,
    const float* __restrict__ qkv_b, const float4* __restrict__ dwq,
    unsigned short* __restrict__ qkvd, unsigned short* __restrict__ vT)
{
  __shared__ __align__(16) char smem[34816];
  unsigned short* Bs   = (unsigned short*)smem;   // [128][136] staged x rows
  unsigned short* pres = (unsigned short*)smem;   // bf16 pre-dw tile (alias)

  const int t = threadIdx.x;
  const int otile = blockIdx.x, ytile = blockIdx.y, b = blockIdx.z;
  const int obase = otile * 128;
  const int ybase = ytile * 124;                  // first output y (even)
  const int wv = t >> 6, l = t & 63, quad = l >> 4, lm = l & 15;
  const bool interior = (ytile >= 1 && ytile <= 32);

  // hoist A-operand (weights) into registers; latency hides under staging
  const unsigned short* wbase =
      qkv_wb + (size_t)(obase + wv * 32 + lm) * CD + quad * 8;
  bf16x8 wa0[4], wa1[4];
#pragma unroll
  for (int ks = 0; ks < 4; ks++) {
    wa0[ks] = *(const bf16x8*)(wbase + ks * 32);
    wa1[ks] = *(const bf16x8*)(wbase + 16 * CD + ks * 32);
  }

  // stage B: rows i=0..127 <-> y = ybase-2+i (zero outside [0,N))
  if (interior) {
#pragma unroll
    for (int i = 0; i < 8; i++) {
      int f = i * 256 + t;
      int row = f >> 4, c8 = (f & 15) * 8;
      *(uint4*)&Bs[row * 136 + c8] =
          *(const uint4*)(xT + ((size_t)b * N + ybase - 2 + row) * CD + c8);
    }
  } else {
#pragma unroll
    for (int i = 0; i < 8; i++) {
      int f = i * 256 + t;
      int row = f >> 4, c8 = (f & 15) * 8;
      int yg = ybase - 2 + row;
      uint4 v = make_uint4(0u, 0u, 0u, 0u);
      if (yg >= 0 && yg < N)
        v = *(const uint4*)(xT + ((size_t)b * N + yg) * CD + c8);
      *(uint4*)&Bs[row * 136 + c8] = v;
    }
  }
  __syncthreads();

  floatx4 acc[2][8];
#pragma unroll
  for (int mt = 0; mt < 2; mt++)
#pragma unroll
    for (int nt = 0; nt < 8; nt++) acc[mt][nt] = (floatx4){0.f, 0.f, 0.f, 0.f};

#pragma unroll
  for (int ks = 0; ks < 4; ks++) {
#pragma unroll
    for (int nt = 0; nt < 8; nt++) {
      bf16x8 bb = *(const bf16x8*)&Bs[(nt * 16 + lm) * 136 + ks * 32 + quad * 8];
      acc[0][nt] = MFMA16(wa0[ks], bb, acc[0][nt]);
      acc[1][nt] = MFMA16(wa1[ks], bb, acc[1][nt]);
    }
  }

  if (otile < 2) {
    // ---- q,k: pres[o][j] (j = local row - 1, j in [0,126]), stride 132
    __syncthreads();
    if (interior) {
#pragma unroll
      for (int mt = 0; mt < 2; mt++)
#pragma unroll
        for (int r = 0; r < 4; r++) {
          int o = wv * 32 + mt * 16 + quad * 4 + r;
          float bias = qkv_b[obase + o];
#pragma unroll
          for (int nt = 0; nt < 8; nt++) {
            int i = nt * 16 + lm;
            if (i >= 1) pres[o * 132 + (i - 1)] = f2b(acc[mt][nt][r] + bias);
          }
        }
    } else {
#pragma unroll
      for (int mt = 0; mt < 2; mt++)
#pragma unroll
        for (int r = 0; r < 4; r++) {
          int o = wv * 32 + mt * 16 + quad * 4 + r;
          float bias = qkv_b[obase + o];
#pragma unroll
          for (int nt = 0; nt < 8; nt++) {
            int i = nt * 16 + lm;
            if (i >= 1) {
              int yg = ybase - 2 + i;
              pres[o * 132 + (i - 1)] =
                  f2b((yg >= 0 && yg < N) ? (acc[mt][nt][r] + bias) : 0.f);
            }
          }
        }
    }
    __syncthreads();
    // y-pair sweep: wave-uniform o, lanes cover 62 aligned pairs
    const int p = t & 63, og = t >> 6;
    const bool ok = (p < 62) && (ybase + 2 * p < N);
    const unsigned int* presu = (const unsigned int*)pres;  // pairs of bf16
    for (int r2 = 0; r2 < 32; r2++) {
      int oo = __builtin_amdgcn_readfirstlane(obase + og * 32 + r2);
      float4 wq = dwq[oo];                        // {w0,w1,w2,db}
      int o = oo - obase;
      unsigned int u0 = presu[o * 66 + p];
      unsigned int u1 = presu[o * 66 + p + 1];
      float v0 = b2f(u0), v1 = b2fh(u0), v2 = b2f(u1), v3 = b2fh(u1);
      float out0 = wq.x * v0 + wq.y * v1 + wq.z * v2 + wq.w;
      float out1 = wq.x * v1 + wq.y * v2 + wq.z * v3 + wq.w;
      unsigned int pk = (unsigned int)f2b(out0) |
                        ((unsigned int)f2b(out1) << 16);
      if (ok)
        *(unsigned int*)(qkvd + ((size_t)b * 256 + oo) * N + ybase + 2 * p) = pk;
    }
  } else {
    // ---- v: pres[i][o], stride 132; o-pair per lane, quarter y-range
    const int op = t & 63, quarter = t >> 6;
    const int o0 = 2 * op;
    const float4 wqa = dwq[256 + o0];
    const float4 wqb = dwq[256 + o0 + 1];
    __syncthreads();
    if (interior) {
#pragma unroll
      for (int mt = 0; mt < 2; mt++)
#pragma unroll
        for (int r = 0; r < 4; r++) {
          int o2 = wv * 32 + mt * 16 + quad * 4 + r;
          float bias = qkv_b[obase + o2];
#pragma unroll
          for (int nt = 0; nt < 8; nt++) {
            int i = nt * 16 + lm;
            pres[i * 132 + o2] = f2b(acc[mt][nt][r] + bias);
          }
        }
    } else {
#pragma unroll
      for (int mt = 0; mt < 2; mt++)
#pragma unroll
        for (int r = 0; r < 4; r++) {
          int o2 = wv * 32 + mt * 16 + quad * 4 + r;
          float bias = qkv_b[obase + o2];
#pragma unroll
          for (int nt = 0; nt < 8; nt++) {
            int i = nt * 16 + lm;
            int yg = ybase - 2 + i;
            pres[i * 132 + o2] =
                f2b((yg >= 0 && yg < N) ? (acc[mt][nt][r] + bias) : 0.f);
          }
        }
    }
    __syncthreads();
    const unsigned int* pu = (const unsigned int*)pres;   // [i][o-pair]
    int i0 = 2 + quarter * 31;                  // quarters: 31 rows each
    unsigned int pm = pu[(i0 - 1) * 66 + op];
    unsigned int pc = pu[i0 * 66 + op];
    if (interior) {
      for (int i = i0; i < i0 + 31; i++) {
        unsigned int pp = pu[(i + 1) * 66 + op];
        int yo = ybase - 2 + i;
        float a0 = wqa.x * b2f(pm) + wqa.y * b2f(pc) + wqa.z * b2f(pp) + wqa.w;
        float a1 = wqb.x * b2fh(pm) + wqb.y * b2fh(pc) + wqb.z * b2fh(pp) + wqb.w;
        unsigned int pk = (unsigned int)f2b(a0) | ((unsigned int)f2b(a1) << 16);
        *(unsigned int*)(vT + ((size_t)b * N + yo) * CD + o0) = pk;
        pm = pc; pc = pp;
      }
    } else {
      for (int i = i0; i < i0 + 31; i++) {
        unsigned int pp = pu[(i + 1) * 66 + op];
        int yo = ybase - 2 + i;
        if (yo >= 0 && yo < N) {
          float a0 = wqa.x * b2f(pm) + wqa.y * b2f(pc) + wqa.z * b2f(pp) + wqa.w;
          float a1 = wqb.x * b2fh(pm) + wqb.y * b2fh(pc) + wqb.z * b2fh(pp) + wqb.w;
          unsigned int pk = (unsigned int)f2b(a0) | ((unsigned int)f2b(a1) << 16);
          *(unsigned int*)(vT + ((size_t)b * N + yo) * CD + o0) = pk;
        }
        pm = pc; pc = pp;
      }
    }
  }
}

// ---------------------------------------------------------------------------
// K3 (fused with K45): MFMA Gram partials -> part, then the LAST block per
// batch (device-scope threadfence-reduction, counter in d_out) runs the
// former k45 inline: sum partials, normalize+temperature, exact top-k ranks,
// fold 4 masked softmaxes -> AwtT bf16, M = proj_w @ blockdiag(A) -> Mb.
// grid (4, H, B), 256 thr. LDS = 50,176 B union -> 2 blocks/CU (matches
// 512-block grid on 256 CUs).
// ---------------------------------------------------------------------------
__global__ __launch_bounds__(256, 2) void k3_gram(
    const unsigned short* __restrict__ qkvd, float* __restrict__ part,
    const unsigned short* __restrict__ proj_wb,
    const float* __restrict__ temperature, const float* __restrict__ attn_w,
    unsigned short* __restrict__ Mb, unsigned int* __restrict__ cnt)
{
  __shared__ __align__(16) char sm[50176];
  __shared__ int isLast;
  float* red = (float*)sm;             // [wv][tile][row*17+col], 34,816 B
  const int ns = blockIdx.x, h = blockIdx.y, b = blockIdx.z;
  const int t = threadIdx.x;
  const int wv = t >> 6, l = t & 63, quad = l >> 4, lm = l & 15;
  const unsigned short* qb = qkvd + ((size_t)b * 256 + h * C_) * N;
  const unsigned short* kb = qkvd + ((size_t)b * 256 + 128 + h * C_) * N;

  floatx4 acc[8];
#pragma unroll
  for (int i = 0; i < 8; i++) acc[i] = (floatx4){0.f, 0.f, 0.f, 0.f};

  const int nbase = ns * 1024 + wv * 32 + quad * 8;
#pragma unroll
  for (int ch = 0; ch < 8; ch++) {
    int nc = nbase + ch * 128;
    bf16x8 a0 = *(const bf16x8*)(qb + (size_t)lm * N + nc);
    bf16x8 a1 = *(const bf16x8*)(qb + (size_t)(16 + lm) * N + nc);
    bf16x8 b0 = *(const bf16x8*)(kb + (size_t)lm * N + nc);
    bf16x8 b1 = *(const bf16x8*)(kb + (size_t)(16 + lm) * N + nc);
    acc[0] = MFMA16(a0, b0, acc[0]);
    acc[1] = MFMA16(a0, b1, acc[1]);
    acc[2] = MFMA16(a1, b0, acc[2]);
    acc[3] = MFMA16(a1, b1, acc[3]);
    acc[4] = MFMA16(a0, a0, acc[4]);
    acc[5] = MFMA16(a1, a1, acc[5]);
    acc[6] = MFMA16(b0, b0, acc[6]);
    acc[7] = MFMA16(b1, b1, acc[7]);
  }

#pragma unroll
  for (int tl = 0; tl < 8; tl++)
#pragma unroll
    for (int r = 0; r < 4; r++)
      red[wv * 2176 + tl * 272 + (quad * 4 + r) * 17 + lm] = acc[tl][r];
  __syncthreads();

  float* pb = part + ((size_t)(b * H_ + h) * 4 + ns) * 2048;
  for (int e = t; e < 2048; e += 256) {
    int tl = e >> 8, rc = e & 255, row = rc >> 4, col = rc & 15;
    int a = tl * 272 + row * 17 + col;
    float s = red[a] + red[2176 + a] + red[2 * 2176 + a] + red[3 * 2176 + a];
    if (tl < 4) {
      int mt = tl >> 1, nt = tl & 1;
      pb[(mt * 16 + row) * 32 + nt * 16 + col] = s;
    } else if (row == col) {
      if (tl < 6) pb[1024 + (tl - 4) * 16 + row] = s;
      else        pb[1056 + (tl - 6) * 16 + row] = s;
    }
  }

  // ---- completion counting: last of 16 blocks per b runs the k45 body ----
  __threadfence();                      // release this block's part stores
  __syncthreads();
  if (t == 0) isLast = (atomicAdd(&cnt[b], 1u) == 15u);
  __syncthreads();
  if (!isLast) return;
  __threadfence();                      // acquire other blocks' part stores

  // ---- former K45, LDS aliased onto sm ----
  float* LaF          = (float*)sm;                        // [4][32][33]
  float* sq2          = (float*)(sm + 16896);              // [256]
  float* rn           = (float*)(sm + 17920);              // [256]
  float* exL          = (float*)(sm + 18944);              // [4][32][33]
  unsigned char* rkL  = (unsigned char*)(sm + 35840);      // [4][32][32]
  unsigned short* Aw  = (unsigned short*)(sm + 39936);     // [4][32][40]
#define LA(hh, ii, jj) LaF[((hh) * C_ + (ii)) * 33 + (jj)]
#define EXL(hh, ii, jj) exL[((hh) * C_ + (ii)) * 33 + (jj)]
#define RKL(hh, ii, jj) rkL[((hh) * C_ + (ii)) * C_ + (jj)]
#define AWT(hh, jj, ii) Aw[((hh) * C_ + (jj)) * 40 + (ii)]

  const float* pbb = part + (size_t)b * 32768;
  for (int e = t; e < 4 * 2048; e += 256) {
    int hh = e >> 11, idx = e & 2047;
    if (idx < 1088) {
      const float* p = pbb + hh * 8192 + idx;
      float s = p[0] + p[2048] + p[2 * 2048] + p[3 * 2048];
      if (idx < 1024) LA(hh, idx >> 5, idx & 31) = s;
      else if (idx < 1056) sq2[hh * 32 + (idx - 1024)] = s;
      else sq2[128 + hh * 32 + (idx - 1056)] = s;
    }
  }
  __syncthreads();
  rn[t] = 1.f / fmaxf(sqrtf(sq2[t]), 1e-12f);
  __syncthreads();
  for (int e = t; e < 4096; e += 256) {
    int hh = e >> 10, i = (e >> 5) & 31, j = e & 31;
    LA(hh, i, j) *= rn[hh * 32 + i] * rn[128 + hh * 32 + j] * temperature[hh];
  }
  __syncthreads();

  if (t < 128) {
    int hh = t >> 5, i = t & 31;
    float m = -1e30f;
    for (int j = 0; j < 32; j++) m = fmaxf(m, LA(hh, i, j));
    float S0 = 0.f, S1 = 0.f, S2 = 0.f, S3 = 0.f;
    for (int j = 0; j < 32; j++) {
      float vj = LA(hh, i, j);
      int r = 0;
      for (int j2 = 0; j2 < 32; j2++) {
        float v2 = LA(hh, i, j2);
        r += (v2 > vj) || (v2 == vj && j2 < j);
      }
      float e = __expf(vj - m);
      EXL(hh, i, j) = e;
      RKL(hh, i, j) = (unsigned char)r;
      if (r < 16) S0 += e;
      if (r < 21) S1 += e;
      if (r < 24) S2 += e;
      if (r < 25) S3 += e;
    }
    float w0 = attn_w[0] / S0, w1 = attn_w[1] / S1;
    float w2 = attn_w[2] / S2, w3 = attn_w[3] / S3;
    for (int j = 0; j < 32; j++) {
      int r = RKL(hh, i, j);
      float cmb = (r < 16 ? w0 : 0.f) + (r < 21 ? w1 : 0.f) +
                  (r < 24 ? w2 : 0.f) + (r < 25 ? w3 : 0.f);
      AWT(hh, j, i) = f2b(EXL(hh, i, j) * cmb);
    }
  }
  __syncthreads();

  {
    const int hh = wv;
    bf16x8 bfr[2];
#pragma unroll
    for (int jt = 0; jt < 2; jt++)
      bfr[jt] = *(const bf16x8*)&AWT(hh, jt * 16 + lm, quad * 8);
#pragma unroll
    for (int mt = 0; mt < 8; mt++) {
      bf16x8 a = *(const bf16x8*)(proj_wb +
                    (size_t)(mt * 16 + lm) * CD + hh * C_ + quad * 8);
#pragma unroll
      for (int jt = 0; jt < 2; jt++) {
        floatx4 ac = (floatx4){0.f, 0.f, 0.f, 0.f};
        ac = MFMA16(a, bfr[jt], ac);
#pragma unroll
        for (int r = 0; r < 4; r++) {
          int row = quad * 4 + r;
          Mb[(size_t)b * 16384 + (mt * 16 + row) * CD + hh * C_ + jt * 16 + lm] =
              f2b(ac[r]);
        }
      }
    }
  }
#undef LA
#undef EXL
#undef RKL
#undef AWT
}

// ---------------------------------------------------------------------------
// K6: out[b] = Mb @ V^T + proj_b. A (Mb) per-ks from global (L2-hot);
// LDS = Bs only -> 4 blocks/CU. grid (32, 32), 256 thr.
// ---------------------------------------------------------------------------
__global__ __launch_bounds__(256, 4) void k6_out(
    const unsigned short* __restrict__ vT, const unsigned short* __restrict__ Mb,
    const float* __restrict__ proj_b, float* __restrict__ out)
{
  __shared__ unsigned short Bs[128 * 136];
  const int t = threadIdx.x;
  const int y0 = blockIdx.x * 128, b = blockIdx.y;
  const int wv = t >> 6, l = t & 63, quad = l >> 4, lm = l & 15;

#pragma unroll
  for (int i = 0; i < 8; i++) {
    int f = i * 256 + t;
    int row = f >> 4, c8 = (f & 15) * 8;
    *(uint4*)&Bs[row * 136 + c8] =
        *(const uint4*)(vT + ((size_t)b * N + y0 + row) * CD + c8);
  }
  __syncthreads();

  floatx4 acc[2][8];
#pragma unroll
  for (int mt = 0; mt < 2; mt++)
#pragma unroll
    for (int nt = 0; nt < 8; nt++) acc[mt][nt] = (floatx4){0.f, 0.f, 0.f, 0.f};

  const unsigned short* mbase =
      Mb + (size_t)b * 16384 + (size_t)(wv * 32 + lm) * CD + quad * 8;
#pragma unroll
  for (int ks = 0; ks < 4; ks++) {
    bf16x8 a0 = *(const bf16x8*)(mbase + ks * 32);
    bf16x8 a1 = *(const bf16x8*)(mbase + 16 * CD + ks * 32);
#pragma unroll
    for (int nt = 0; nt < 8; nt++) {
      bf16x8 bb = *(const bf16x8*)&Bs[(nt * 16 + lm) * 136 + ks * 32 + quad * 8];
      acc[0][nt] = MFMA16(a0, bb, acc[0][nt]);
      acc[1][nt] = MFMA16(a1, bb, acc[1][nt]);
    }
  }

#pragma unroll
  for (int mt = 0; mt < 2; mt++)
#pragma unroll
    for (int r = 0; r < 4; r++) {
      int o = wv * 32 + mt * 16 + quad * 4 + r;
      float pb = proj_b[o];
#pragma unroll
      for (int nt = 0; nt < 8; nt++) {
        int y = y0 + nt * 16 + lm;
        out[((size_t)b * CD + o) * N + y] = acc[mt][nt][r] + pb;
      }
    }
}

extern "C" void kernel_launch(void* const* d_in, const int* in_sizes, int n_in,
                              void* d_out, int out_size, void* d_ws, size_t ws_size,
                              hipStream_t stream)
{
  (void)in_sizes; (void)n_in; (void)out_size; (void)ws_size;
  const float* x           = (const float*)d_in[0];
  const float* qkv_w       = (const float*)d_in[1];
  const float* qkv_b       = (const float*)d_in[2];
  const float* dw_w        = (const float*)d_in[3];
  const float* dw_b        = (const float*)d_in[4];
  const float* proj_w      = (const float*)d_in[5];
  const float* proj_b      = (const float*)d_in[6];
  const float* temperature = (const float*)d_in[7];
  const float* attn_w      = (const float*)d_in[8];
  float* out = (float*)d_out;

  unsigned short* xT      = (unsigned short*)d_ws;   // 16,777,216 sh
  unsigned short* qkv_wb  = xT + (size_t)16777216;   //     49,152
  unsigned short* proj_wb = qkv_wb + 49152;          //     16,384
  unsigned short* qkvd    = proj_wb + 16384;         // 33,554,432 (q,k)
  unsigned short* vT      = qkvd + (size_t)33554432; // 16,777,216
  unsigned short* Mb      = vT + (size_t)16777216;   //    524,288
  float* part = (float*)(Mb + 524288);               //  1,048,576 f
  // dwq (384 float4 = 6 KiB) aliases Mb: written by k0_xt, read by k1,
  // dead before the k3 tail writes Mb.
  float4* dwq = (float4*)Mb;
  // Per-batch completion counters live in d_out (zeroed by k0_xt each
  // iteration, consumed by k3, fully overwritten by k6's stores).
  unsigned int* cnt = (unsigned int*)d_out;

  k0_xt    <<<dim3(64, 4, 32),  256, 0, stream>>>(x, xT, qkv_w, proj_w, dw_w,
                                                  dw_b, qkv_wb, proj_wb, dwq,
                                                  cnt);
  k1_qkv_dw<<<dim3(3, 34, 32),  256, 0, stream>>>(xT, qkv_wb, qkv_b, dwq,
                                                  qkvd, vT);
  k3_gram  <<<dim3(4, H_, B_),  256, 0, stream>>>(qkvd, part, proj_wb,
                                                  temperature, attn_w, Mb, cnt);
  k6_out   <<<dim3(32, B_),     256, 0, stream>>>(vT, Mb, proj_b, out);
}

// Round 6
// 251.396 us; speedup vs baseline: 1.2414x; 1.2414x over previous
//
#include <hip/hip_runtime.h>

#define B_ 32
#define CD 128
#define O3 384
#define N  4096
#define H_ 4
#define C_ 32

typedef __bf16 bf16x8 __attribute__((ext_vector_type(8)));
typedef float floatx4 __attribute__((ext_vector_type(4)));

#define MFMA16(a, b, c) __builtin_amdgcn_mfma_f32_16x16x32_bf16(a, b, c, 0, 0, 0)

__device__ __forceinline__ float b2f(unsigned int u) {   // low 16 bits
  return __builtin_bit_cast(float, u << 16);
}
__device__ __forceinline__ float b2fh(unsigned int u) {  // high 16 bits
  return __builtin_bit_cast(float, u & 0xffff0000u);
}
__device__ __forceinline__ unsigned short f2b(float f) {
  unsigned int bits = __builtin_bit_cast(unsigned int, f);
  unsigned int r = (bits + 0x7FFFu + ((bits >> 16) & 1u)) >> 16;
  return (unsigned short)r;
}

// ---------------------------------------------------------------------------
// K0: transpose+convert x [b][c][n] fp32 -> xT [b][n][c] bf16, PLUS (on 66
// blocks of the z==0,y<2 plane) weight conversion side-work (pure data-
// parallel, no sync). grid (64, 4, 32), 256 thr.
// ---------------------------------------------------------------------------
__global__ __launch_bounds__(256) void k0_xt(
    const float* __restrict__ x, unsigned short* __restrict__ xT,
    const float* __restrict__ qkv_w, const float* __restrict__ proj_w,
    const float* __restrict__ dw_w, const float* __restrict__ dw_b,
    unsigned short* __restrict__ qkv_wb, unsigned short* __restrict__ proj_wb,
    float4* __restrict__ dwq)
{
  __shared__ float xt[32 * 68];
  const int t = threadIdx.x;
  const int n0 = blockIdx.x * 64, c0 = blockIdx.y * 32, b = blockIdx.z;
  const float* xb = x + ((size_t)b * CD + c0) * N + n0;
#pragma unroll
  for (int i = 0; i < 2; i++) {
    int f = i * 256 + t;
    int c = f >> 4, n4 = (f & 15) * 4;
    float4 v = *(const float4*)(xb + (size_t)c * N + n4);
    *(float4*)&xt[c * 68 + n4] = v;
  }

  // ---- weight-conversion side work (66 blocks) ----
  if (blockIdx.z == 0 && blockIdx.y < 2) {
    int wid = blockIdx.y * 64 + blockIdx.x;
    if (wid < 66) {
      int e = (wid * 256 + t) * 4;
      if (e < 49152) {
        float4 v = *(const float4*)(qkv_w + e);
        unsigned short tmp[4] = {f2b(v.x), f2b(v.y), f2b(v.z), f2b(v.w)};
        *(uint2*)(qkv_wb + e) = *(uint2*)tmp;
      } else if (e < 65536) {
        int off = e - 49152;
        float4 v = *(const float4*)(proj_w + off);
        unsigned short tmp[4] = {f2b(v.x), f2b(v.y), f2b(v.z), f2b(v.w)};
        *(uint2*)(proj_wb + off) = *(uint2*)tmp;
      } else {
        int o = (e - 65536) >> 2;
        if (o < 384)
          dwq[o] = make_float4(dw_w[o * 9 + 1], dw_w[o * 9 + 4],
                               dw_w[o * 9 + 7], dw_b[o]);
      }
    }
  }

  __syncthreads();
  int n = t >> 2, cb = (t & 3) * 8;
  unsigned short tmp[8];
#pragma unroll
  for (int j = 0; j < 8; j++) tmp[j] = f2b(xt[(cb + j) * 68 + n]);
  *(uint4*)(xT + ((size_t)b * N + n0 + n) * CD + c0 + cb) = *(uint4*)tmp;
}

// ---------------------------------------------------------------------------
// K1: MFMA GEMM (128o x 124y outputs, 128 staged rows incl. 2+2 halo, K=128)
// + bias + 3-tap depthwise + bias. Proven round-3/4 structure:
//  - grid (3,34,32) otile-fastest (xT tile sharers adjacent -> L2 hits)
//  - weight fragments hoisted to VGPRs before the staging barrier
//  - interior/edge specialization of both pres scatter phases
//  - q,k epilogue: packed y-pair sweep; v epilogue: o-pair dword sweep
// LDS 34,816 B -> 4 blocks/CU.
// ---------------------------------------------------------------------------
__global__ __launch_bounds__(256, 4) void k1_qkv_dw(
    const unsigned short* __restrict__ xT, const unsigned short* __restrict__ qkv_wb,
    const float* __restrict__ qkv_b, const float4* __restrict__ dwq,
    unsigned short* __restrict__ qkvd, unsigned short* __restrict__ vT)
{
  __shared__ __align__(16) char smem[34816];
  unsigned short* Bs   = (unsigned short*)smem;   // [128][136] staged x rows
  unsigned short* pres = (unsigned short*)smem;   // bf16 pre-dw tile (alias)

  const int t = threadIdx.x;
  const int otile = blockIdx.x, ytile = blockIdx.y, b = blockIdx.z;
  const int obase = otile * 128;
  const int ybase = ytile * 124;                  // first output y (even)
  const int wv = t >> 6, l = t & 63, quad = l >> 4, lm = l & 15;
  const bool interior = (ytile >= 1 && ytile <= 32);

  // hoist A-operand (weights) into registers; latency hides under staging
  const unsigned short* wbase =
      qkv_wb + (size_t)(obase + wv * 32 + lm) * CD + quad * 8;
  bf16x8 wa0[4], wa1[4];
#pragma unroll
  for (int ks = 0; ks < 4; ks++) {
    wa0[ks] = *(const bf16x8*)(wbase + ks * 32);
    wa1[ks] = *(const bf16x8*)(wbase + 16 * CD + ks * 32);
  }

  // stage B: rows i=0..127 <-> y = ybase-2+i (zero outside [0,N))
  if (interior) {
#pragma unroll
    for (int i = 0; i < 8; i++) {
      int f = i * 256 + t;
      int row = f >> 4, c8 = (f & 15) * 8;
      *(uint4*)&Bs[row * 136 + c8] =
          *(const uint4*)(xT + ((size_t)b * N + ybase - 2 + row) * CD + c8);
    }
  } else {
#pragma unroll
    for (int i = 0; i < 8; i++) {
      int f = i * 256 + t;
      int row = f >> 4, c8 = (f & 15) * 8;
      int yg = ybase - 2 + row;
      uint4 v = make_uint4(0u, 0u, 0u, 0u);
      if (yg >= 0 && yg < N)
        v = *(const uint4*)(xT + ((size_t)b * N + yg) * CD + c8);
      *(uint4*)&Bs[row * 136 + c8] = v;
    }
  }
  __syncthreads();

  floatx4 acc[2][8];
#pragma unroll
  for (int mt = 0; mt < 2; mt++)
#pragma unroll
    for (int nt = 0; nt < 8; nt++) acc[mt][nt] = (floatx4){0.f, 0.f, 0.f, 0.f};

#pragma unroll
  for (int ks = 0; ks < 4; ks++) {
#pragma unroll
    for (int nt = 0; nt < 8; nt++) {
      bf16x8 bb = *(const bf16x8*)&Bs[(nt * 16 + lm) * 136 + ks * 32 + quad * 8];
      acc[0][nt] = MFMA16(wa0[ks], bb, acc[0][nt]);
      acc[1][nt] = MFMA16(wa1[ks], bb, acc[1][nt]);
    }
  }

  if (otile < 2) {
    // ---- q,k: pres[o][j] (j = local row - 1, j in [0,126]), stride 132
    __syncthreads();
    if (interior) {
#pragma unroll
      for (int mt = 0; mt < 2; mt++)
#pragma unroll
        for (int r = 0; r < 4; r++) {
          int o = wv * 32 + mt * 16 + quad * 4 + r;
          float bias = qkv_b[obase + o];
#pragma unroll
          for (int nt = 0; nt < 8; nt++) {
            int i = nt * 16 + lm;
            if (i >= 1) pres[o * 132 + (i - 1)] = f2b(acc[mt][nt][r] + bias);
          }
        }
    } else {
#pragma unroll
      for (int mt = 0; mt < 2; mt++)
#pragma unroll
        for (int r = 0; r < 4; r++) {
          int o = wv * 32 + mt * 16 + quad * 4 + r;
          float bias = qkv_b[obase + o];
#pragma unroll
          for (int nt = 0; nt < 8; nt++) {
            int i = nt * 16 + lm;
            if (i >= 1) {
              int yg = ybase - 2 + i;
              pres[o * 132 + (i - 1)] =
                  f2b((yg >= 0 && yg < N) ? (acc[mt][nt][r] + bias) : 0.f);
            }
          }
        }
    }
    __syncthreads();
    // y-pair sweep: wave-uniform o, lanes cover 62 aligned pairs
    const int p = t & 63, og = t >> 6;
    const bool ok = (p < 62) && (ybase + 2 * p < N);
    const unsigned int* presu = (const unsigned int*)pres;  // pairs of bf16
    for (int r2 = 0; r2 < 32; r2++) {
      int oo = __builtin_amdgcn_readfirstlane(obase + og * 32 + r2);
      float4 wq = dwq[oo];                        // {w0,w1,w2,db}
      int o = oo - obase;
      unsigned int u0 = presu[o * 66 + p];
      unsigned int u1 = presu[o * 66 + p + 1];
      float v0 = b2f(u0), v1 = b2fh(u0), v2 = b2f(u1), v3 = b2fh(u1);
      float out0 = wq.x * v0 + wq.y * v1 + wq.z * v2 + wq.w;
      float out1 = wq.x * v1 + wq.y * v2 + wq.z * v3 + wq.w;
      unsigned int pk = (unsigned int)f2b(out0) |
                        ((unsigned int)f2b(out1) << 16);
      if (ok)
        *(unsigned int*)(qkvd + ((size_t)b * 256 + oo) * N + ybase + 2 * p) = pk;
    }
  } else {
    // ---- v: pres[i][o], stride 132; o-pair per lane, quarter y-range
    const int op = t & 63, quarter = t >> 6;
    const int o0 = 2 * op;
    const float4 wqa = dwq[256 + o0];
    const float4 wqb = dwq[256 + o0 + 1];
    __syncthreads();
    if (interior) {
#pragma unroll
      for (int mt = 0; mt < 2; mt++)
#pragma unroll
        for (int r = 0; r < 4; r++) {
          int o2 = wv * 32 + mt * 16 + quad * 4 + r;
          float bias = qkv_b[obase + o2];
#pragma unroll
          for (int nt = 0; nt < 8; nt++) {
            int i = nt * 16 + lm;
            pres[i * 132 + o2] = f2b(acc[mt][nt][r] + bias);
          }
        }
    } else {
#pragma unroll
      for (int mt = 0; mt < 2; mt++)
#pragma unroll
        for (int r = 0; r < 4; r++) {
          int o2 = wv * 32 + mt * 16 + quad * 4 + r;
          float bias = qkv_b[obase + o2];
#pragma unroll
          for (int nt = 0; nt < 8; nt++) {
            int i = nt * 16 + lm;
            int yg = ybase - 2 + i;
            pres[i * 132 + o2] =
                f2b((yg >= 0 && yg < N) ? (acc[mt][nt][r] + bias) : 0.f);
          }
        }
    }
    __syncthreads();
    const unsigned int* pu = (const unsigned int*)pres;   // [i][o-pair]
    int i0 = 2 + quarter * 31;                  // quarters: 31 rows each
    unsigned int pm = pu[(i0 - 1) * 66 + op];
    unsigned int pc = pu[i0 * 66 + op];
    if (interior) {
      for (int i = i0; i < i0 + 31; i++) {
        unsigned int pp = pu[(i + 1) * 66 + op];
        int yo = ybase - 2 + i;
        float a0 = wqa.x * b2f(pm) + wqa.y * b2f(pc) + wqa.z * b2f(pp) + wqa.w;
        float a1 = wqb.x * b2fh(pm) + wqb.y * b2fh(pc) + wqb.z * b2fh(pp) + wqb.w;
        unsigned int pk = (unsigned int)f2b(a0) | ((unsigned int)f2b(a1) << 16);
        *(unsigned int*)(vT + ((size_t)b * N + yo) * CD + o0) = pk;
        pm = pc; pc = pp;
      }
    } else {
      for (int i = i0; i < i0 + 31; i++) {
        unsigned int pp = pu[(i + 1) * 66 + op];
        int yo = ybase - 2 + i;
        if (yo >= 0 && yo < N) {
          float a0 = wqa.x * b2f(pm) + wqa.y * b2f(pc) + wqa.z * b2f(pp) + wqa.w;
          float a1 = wqb.x * b2fh(pm) + wqb.y * b2fh(pc) + wqb.z * b2fh(pp) + wqb.w;
          unsigned int pk = (unsigned int)f2b(a0) | ((unsigned int)f2b(a1) << 16);
          *(unsigned int*)(vT + ((size_t)b * N + yo) * CD + o0) = pk;
        }
        pm = pc; pc = pp;
      }
    }
  }
}

// ---------------------------------------------------------------------------
// K3: MFMA Gram, fragments loaded straight from global (K-major layout),
// no staging barriers. 32x32 QK^T partial over 512 n + Q/K norms via
// self-MFMA diagonals. Split 8 ways (was 4) -> 1024 blocks = 4 blocks/CU
// (latency-bound gather kernel: doubled residency). part[b][h][ns8][2048]
// aliases the dead xT region. grid (8, H, B), 256 thr.
// ---------------------------------------------------------------------------
__global__ __launch_bounds__(256, 4) void k3_gram(
    const unsigned short* __restrict__ qkvd, float* __restrict__ part)
{
  __shared__ float red[4 * 8 * 272];   // [wv][tile][row*17+col]
  const int ns = blockIdx.x, h = blockIdx.y, b = blockIdx.z;
  const int t = threadIdx.x;
  const int wv = t >> 6, l = t & 63, quad = l >> 4, lm = l & 15;
  const unsigned short* qb = qkvd + ((size_t)b * 256 + h * C_) * N;
  const unsigned short* kb = qkvd + ((size_t)b * 256 + 128 + h * C_) * N;

  floatx4 acc[8];
#pragma unroll
  for (int i = 0; i < 8; i++) acc[i] = (floatx4){0.f, 0.f, 0.f, 0.f};

  const int nbase = ns * 512 + wv * 32 + quad * 8;
#pragma unroll
  for (int ch = 0; ch < 4; ch++) {
    int nc = nbase + ch * 128;
    bf16x8 a0 = *(const bf16x8*)(qb + (size_t)lm * N + nc);
    bf16x8 a1 = *(const bf16x8*)(qb + (size_t)(16 + lm) * N + nc);
    bf16x8 b0 = *(const bf16x8*)(kb + (size_t)lm * N + nc);
    bf16x8 b1 = *(const bf16x8*)(kb + (size_t)(16 + lm) * N + nc);
    acc[0] = MFMA16(a0, b0, acc[0]);
    acc[1] = MFMA16(a0, b1, acc[1]);
    acc[2] = MFMA16(a1, b0, acc[2]);
    acc[3] = MFMA16(a1, b1, acc[3]);
    acc[4] = MFMA16(a0, a0, acc[4]);
    acc[5] = MFMA16(a1, a1, acc[5]);
    acc[6] = MFMA16(b0, b0, acc[6]);
    acc[7] = MFMA16(b1, b1, acc[7]);
  }

#pragma unroll
  for (int tl = 0; tl < 8; tl++)
#pragma unroll
    for (int r = 0; r < 4; r++)
      red[wv * 2176 + tl * 272 + (quad * 4 + r) * 17 + lm] = acc[tl][r];
  __syncthreads();

  float* pb = part + ((size_t)(b * H_ + h) * 8 + ns) * 2048;
  for (int e = t; e < 2048; e += 256) {
    int tl = e >> 8, rc = e & 255, row = rc >> 4, col = rc & 15;
    int a = tl * 272 + row * 17 + col;
    float s = red[a] + red[2176 + a] + red[2 * 2176 + a] + red[3 * 2176 + a];
    if (tl < 4) {
      int mt = tl >> 1, nt = tl & 1;
      pb[(mt * 16 + row) * 32 + nt * 16 + col] = s;
    } else if (row == col) {
      if (tl < 6) pb[1024 + (tl - 4) * 16 + row] = s;
      else        pb[1056 + (tl - 6) * 16 + row] = s;
    }
  }
}

// ---------------------------------------------------------------------------
// K45: sum 8 partials, normalize+temperature, exact stable top-k ranks, fold
// 4 masked softmaxes -> AwtT bf16; M = proj_w @ blockdiag(A) via MFMA.
// grid (B), 256 thr.
// ---------------------------------------------------------------------------
__global__ __launch_bounds__(256) void k45(
    const float* __restrict__ part, const unsigned short* __restrict__ proj_wb,
    const float* __restrict__ temperature, const float* __restrict__ attn_w,
    unsigned short* __restrict__ Mb)
{
  __shared__ float La[H_][C_][33];
  __shared__ float sq2[256];
  __shared__ float rn[256];
  __shared__ float exL[H_][C_][33];
  __shared__ unsigned char rkL[H_][C_][C_];
  __shared__ unsigned short AwtT[H_][C_][40];
  const int b = blockIdx.x, t = threadIdx.x;

  const float* pbb = part + (size_t)b * 65536;
  for (int e = t; e < 4 * 2048; e += 256) {
    int h = e >> 11, idx = e & 2047;
    if (idx < 1088) {
      const float* p = pbb + h * 16384 + idx;
      float s = 0.f;
#pragma unroll
      for (int j = 0; j < 8; j++) s += p[j * 2048];
      if (idx < 1024) La[h][idx >> 5][idx & 31] = s;
      else if (idx < 1056) sq2[h * 32 + (idx - 1024)] = s;
      else sq2[128 + h * 32 + (idx - 1056)] = s;
    }
  }
  __syncthreads();
  rn[t] = 1.f / fmaxf(sqrtf(sq2[t]), 1e-12f);
  __syncthreads();
  for (int e = t; e < 4096; e += 256) {
    int h = e >> 10, i = (e >> 5) & 31, j = e & 31;
    La[h][i][j] *= rn[h * 32 + i] * rn[128 + h * 32 + j] * temperature[h];
  }
  __syncthreads();

  if (t < 128) {
    int h = t >> 5, i = t & 31;
    float m = -1e30f;
    for (int j = 0; j < 32; j++) m = fmaxf(m, La[h][i][j]);
    float S0 = 0.f, S1 = 0.f, S2 = 0.f, S3 = 0.f;
    for (int j = 0; j < 32; j++) {
      float vj = La[h][i][j];
      int r = 0;
      for (int j2 = 0; j2 < 32; j2++) {
        float v2 = La[h][i][j2];
        r += (v2 > vj) || (v2 == vj && j2 < j);
      }
      float e = __expf(vj - m);
      exL[h][i][j] = e;
      rkL[h][i][j] = (unsigned char)r;
      if (r < 16) S0 += e;
      if (r < 21) S1 += e;
      if (r < 24) S2 += e;
      if (r < 25) S3 += e;
    }
    float w0 = attn_w[0] / S0, w1 = attn_w[1] / S1;
    float w2 = attn_w[2] / S2, w3 = attn_w[3] / S3;
    for (int j = 0; j < 32; j++) {
      int r = rkL[h][i][j];
      float cmb = (r < 16 ? w0 : 0.f) + (r < 21 ? w1 : 0.f) +
                  (r < 24 ? w2 : 0.f) + (r < 25 ? w3 : 0.f);
      AwtT[h][j][i] = f2b(exL[h][i][j] * cmb);
    }
  }
  __syncthreads();

  {
    const int wv = t >> 6, l = t & 63, quad = l >> 4, lm = l & 15;
    const int h = wv;
    bf16x8 bfr[2];
#pragma unroll
    for (int jt = 0; jt < 2; jt++)
      bfr[jt] = *(const bf16x8*)&AwtT[h][jt * 16 + lm][quad * 8];
#pragma unroll
    for (int mt = 0; mt < 8; mt++) {
      bf16x8 a = *(const bf16x8*)(proj_wb +
                    (size_t)(mt * 16 + lm) * CD + h * C_ + quad * 8);
#pragma unroll
      for (int jt = 0; jt < 2; jt++) {
        floatx4 acc = (floatx4){0.f, 0.f, 0.f, 0.f};
        acc = MFMA16(a, bfr[jt], acc);
#pragma unroll
        for (int r = 0; r < 4; r++) {
          int row = quad * 4 + r;
          Mb[(size_t)b * 16384 + (mt * 16 + row) * CD + h * C_ + jt * 16 + lm] =
              f2b(acc[r]);
        }
      }
    }
  }
}

// ---------------------------------------------------------------------------
// K6: out[b] = Mb @ V^T + proj_b. A (Mb) per-ks from global (L2-hot);
// LDS = Bs only -> 4 blocks/CU. grid (32, 32), 256 thr.
// ---------------------------------------------------------------------------
__global__ __launch_bounds__(256, 4) void k6_out(
    const unsigned short* __restrict__ vT, const unsigned short* __restrict__ Mb,
    const float* __restrict__ proj_b, float* __restrict__ out)
{
  __shared__ unsigned short Bs[128 * 136];
  const int t = threadIdx.x;
  const int y0 = blockIdx.x * 128, b = blockIdx.y;
  const int wv = t >> 6, l = t & 63, quad = l >> 4, lm = l & 15;

#pragma unroll
  for (int i = 0; i < 8; i++) {
    int f = i * 256 + t;
    int row = f >> 4, c8 = (f & 15) * 8;
    *(uint4*)&Bs[row * 136 + c8] =
        *(const uint4*)(vT + ((size_t)b * N + y0 + row) * CD + c8);
  }
  __syncthreads();

  floatx4 acc[2][8];
#pragma unroll
  for (int mt = 0; mt < 2; mt++)
#pragma unroll
    for (int nt = 0; nt < 8; nt++) acc[mt][nt] = (floatx4){0.f, 0.f, 0.f, 0.f};

  const unsigned short* mbase =
      Mb + (size_t)b * 16384 + (size_t)(wv * 32 + lm) * CD + quad * 8;
#pragma unroll
  for (int ks = 0; ks < 4; ks++) {
    bf16x8 a0 = *(const bf16x8*)(mbase + ks * 32);
    bf16x8 a1 = *(const bf16x8*)(mbase + 16 * CD + ks * 32);
#pragma unroll
    for (int nt = 0; nt < 8; nt++) {
      bf16x8 bb = *(const bf16x8*)&Bs[(nt * 16 + lm) * 136 + ks * 32 + quad * 8];
      acc[0][nt] = MFMA16(a0, bb, acc[0][nt]);
      acc[1][nt] = MFMA16(a1, bb, acc[1][nt]);
    }
  }

#pragma unroll
  for (int mt = 0; mt < 2; mt++)
#pragma unroll
    for (int r = 0; r < 4; r++) {
      int o = wv * 32 + mt * 16 + quad * 4 + r;
      float pb = proj_b[o];
#pragma unroll
      for (int nt = 0; nt < 8; nt++) {
        int y = y0 + nt * 16 + lm;
        out[((size_t)b * CD + o) * N + y] = acc[mt][nt][r] + pb;
      }
    }
}

extern "C" void kernel_launch(void* const* d_in, const int* in_sizes, int n_in,
                              void* d_out, int out_size, void* d_ws, size_t ws_size,
                              hipStream_t stream)
{
  (void)in_sizes; (void)n_in; (void)out_size; (void)ws_size;
  const float* x           = (const float*)d_in[0];
  const float* qkv_w       = (const float*)d_in[1];
  const float* qkv_b       = (const float*)d_in[2];
  const float* dw_w        = (const float*)d_in[3];
  const float* dw_b        = (const float*)d_in[4];
  const float* proj_w      = (const float*)d_in[5];
  const float* proj_b      = (const float*)d_in[6];
  const float* temperature = (const float*)d_in[7];
  const float* attn_w      = (const float*)d_in[8];
  float* out = (float*)d_out;

  unsigned short* xT      = (unsigned short*)d_ws;   // 16,777,216 sh
  unsigned short* qkv_wb  = xT + (size_t)16777216;   //     49,152
  unsigned short* proj_wb = qkv_wb + 49152;          //     16,384
  unsigned short* qkvd    = proj_wb + 16384;         // 33,554,432 (q,k)
  unsigned short* vT      = qkvd + (size_t)33554432; // 16,777,216
  unsigned short* Mb      = vT + (size_t)16777216;   //    524,288
  // part (8 MB: 32 b x 4 h x 8 ns x 2048 f) ALIASES xT: xT is dead after
  // k1; part is written by k3, read by k45. Lifetimes disjoint.
  float* part = (float*)xT;
  // dwq (384 float4 = 6 KiB) aliases Mb: written by k0_xt, read by k1,
  // dead before k45 writes Mb. 16B-aligned (Mb offset is 16B-multiple).
  float4* dwq = (float4*)Mb;

  k0_xt    <<<dim3(64, 4, 32),  256, 0, stream>>>(x, xT, qkv_w, proj_w, dw_w,
                                                  dw_b, qkv_wb, proj_wb, dwq);
  k1_qkv_dw<<<dim3(3, 34, 32),  256, 0, stream>>>(xT, qkv_wb, qkv_b, dwq,
                                                  qkvd, vT);
  k3_gram  <<<dim3(8, H_, B_),  256, 0, stream>>>(qkvd, part);
  k45      <<<dim3(B_),         256, 0, stream>>>(part, proj_wb, temperature,
                                                  attn_w, Mb);
  k6_out   <<<dim3(32, B_),     256, 0, stream>>>(vT, Mb, proj_b, out);
}

// Round 7
// 234.892 us; speedup vs baseline: 1.3286x; 1.0703x over previous
//
#include <hip/hip_runtime.h>

#define B_ 32
#define CD 128
#define O3 384
#define N  4096
#define H_ 4
#define C_ 32

typedef __bf16 bf16x8 __attribute__((ext_vector_type(8)));
typedef float floatx4 __attribute__((ext_vector_type(4)));

#define MFMA16(a, b, c) __builtin_amdgcn_mfma_f32_16x16x32_bf16(a, b, c, 0, 0, 0)

__device__ __forceinline__ float b2f(unsigned int u) {   // low 16 bits
  return __builtin_bit_cast(float, u << 16);
}
__device__ __forceinline__ float b2fh(unsigned int u) {  // high 16 bits
  return __builtin_bit_cast(float, u & 0xffff0000u);
}
__device__ __forceinline__ unsigned short f2b(float f) {
  unsigned int bits = __builtin_bit_cast(unsigned int, f);
  unsigned int r = (bits + 0x7FFFu + ((bits >> 16) & 1u)) >> 16;
  return (unsigned short)r;
}

// ---------------------------------------------------------------------------
// K0: transpose+convert x [b][c][n] fp32 -> xT [b][n][c] bf16, PLUS side-work
// on the z==0,y<2 plane (128 blocks): weight conversions (wid<66), fused-dw
// coefficient tables for the qk path (wid==66), and part2 zeroing (wid>=67).
// grid (64, 4, 32), 256 thr.
// ---------------------------------------------------------------------------
__global__ __launch_bounds__(256) void k0_xt(
    const float* __restrict__ x, unsigned short* __restrict__ xT,
    const float* __restrict__ qkv_w, const float* __restrict__ proj_w,
    const float* __restrict__ dw_w, const float* __restrict__ dw_b,
    const float* __restrict__ qkv_b,
    unsigned short* __restrict__ qkv_wb, unsigned short* __restrict__ proj_wb,
    float4* __restrict__ dwq, float4* __restrict__ dwq2,
    float* __restrict__ c0a, float* __restrict__ c2a,
    float* __restrict__ part2)
{
  __shared__ float xt[32 * 68];
  const int t = threadIdx.x;
  const int n0 = blockIdx.x * 64, c0 = blockIdx.y * 32, b = blockIdx.z;
  const float* xb = x + ((size_t)b * CD + c0) * N + n0;
#pragma unroll
  for (int i = 0; i < 2; i++) {
    int f = i * 256 + t;
    int c = f >> 4, n4 = (f & 15) * 4;
    float4 v = *(const float4*)(xb + (size_t)c * N + n4);
    *(float4*)&xt[c * 68 + n4] = v;
  }

  if (blockIdx.z == 0 && blockIdx.y < 2) {
    int wid = blockIdx.y * 64 + blockIdx.x;
    if (wid < 66) {
      int e = (wid * 256 + t) * 4;
      if (e < 49152) {
        float4 v = *(const float4*)(qkv_w + e);
        unsigned short tmp[4] = {f2b(v.x), f2b(v.y), f2b(v.z), f2b(v.w)};
        *(uint2*)(qkv_wb + e) = *(uint2*)tmp;
      } else if (e < 65536) {
        int off = e - 49152;
        float4 v = *(const float4*)(proj_w + off);
        unsigned short tmp[4] = {f2b(v.x), f2b(v.y), f2b(v.z), f2b(v.w)};
        *(uint2*)(proj_wb + off) = *(uint2*)tmp;
      } else {
        int o = (e - 65536) >> 2;
        if (o < 384)
          dwq[o] = make_float4(dw_w[o * 9 + 1], dw_w[o * 9 + 4],
                               dw_w[o * 9 + 7], dw_b[o]);
      }
    } else if (wid == 66) {
      int o = t;    // 256 threads cover q,k channels 0..255
      float w0 = dw_w[o * 9 + 1], w1 = dw_w[o * 9 + 4], w2 = dw_w[o * 9 + 7];
      float qb = qkv_b[o];
      dwq2[o] = make_float4(w0, w1, w2, qb * (w0 + w1 + w2) + dw_b[o]);
      c0a[o] = qb * w0;
      c2a[o] = qb * w2;
    } else {      // wid 67..127: zero part2 (32*4*1088 floats = 34816 uint4)
      int idx = (wid - 67) * 256 + t;
      uint4 z4 = make_uint4(0u, 0u, 0u, 0u);
      for (int k2 = idx; k2 < 34816; k2 += 61 * 256)
        ((uint4*)part2)[k2] = z4;
    }
  }

  __syncthreads();
  int n = t >> 2, cb = (t & 3) * 8;
  unsigned short tmp[8];
#pragma unroll
  for (int j = 0; j < 8; j++) tmp[j] = f2b(xt[(cb + j) * 68 + n]);
  *(uint4*)(xT + ((size_t)b * N + n0 + n) * CD + c0 + cb) = *(uint4*)tmp;
}

// ---------------------------------------------------------------------------
// K1: two block flavors, grid (101, 32):
//  x<67: qk block (M=256 = q+k channels, y-window 62, K=128). Raw GEMM into
//   regs, 3-tap dw applied IN-REGISTER via 16-lane-group shuffles (C cols are
//   y=lm; bias folded: sb=qkv_b*(w0+w1+w2)+dw_b, edge c0/c2 at y=0/N-1).
//   Post-dw q,k -> LDS only (pres2 [256][68] bf16, aliases staging tile).
//   Then wave=head computes 32x32 QK^T + q/k norm diagonals via MFMA over
//   K=64 (cols 62,63 zeroed) and atomicAdds the 1088-float partial into
//   part2[b][h]. q,k NEVER touch HBM.
//  x>=67: v block (window 124, obase=256) -- proven round-6 path, writes vT.
// LDS 34,816 B. qkvd and k3 are eliminated.
// ---------------------------------------------------------------------------
__global__ __launch_bounds__(256, 3) void k1_qkv_dw(
    const unsigned short* __restrict__ xT, const unsigned short* __restrict__ qkv_wb,
    const float* __restrict__ qkv_b, const float4* __restrict__ dwq,
    const float4* __restrict__ dwq2, const float* __restrict__ c0a,
    const float* __restrict__ c2a, unsigned short* __restrict__ vT,
    float* part2)
{
  __shared__ __align__(16) char smem[34816];
  const int t = threadIdx.x;
  const int b = blockIdx.y;
  const int wv = t >> 6, l = t & 63, quad = l >> 4, lm = l & 15;

  if (blockIdx.x < 67) {
    // ==================== qk block ====================
    unsigned short* Bs    = (unsigned short*)smem;   // [64][136] staged rows
    unsigned short* pres2 = (unsigned short*)smem;   // [256][68] post-dw (alias)
    const int yw = blockIdx.x;
    const int ybase = yw * 62;
    const bool interior = (yw >= 1 && yw <= 65);

    // hoist weights: rows o = wv*64 + mt*16 + lm
    const unsigned short* wbase = qkv_wb + (size_t)(wv * 64 + lm) * CD + quad * 8;
    bf16x8 wa[4][4];
#pragma unroll
    for (int mt = 0; mt < 4; mt++)
#pragma unroll
      for (int ks = 0; ks < 4; ks++)
        wa[mt][ks] = *(const bf16x8*)(wbase + (size_t)mt * 16 * CD + ks * 32);

    // stage rows i=0..63 <-> y = ybase-1+i (zero outside [0,N))
    if (interior) {
#pragma unroll
      for (int i = 0; i < 4; i++) {
        int f = i * 256 + t;
        int row = f >> 4, c8 = (f & 15) * 8;
        *(uint4*)&Bs[row * 136 + c8] =
            *(const uint4*)(xT + ((size_t)b * N + ybase - 1 + row) * CD + c8);
      }
    } else {
#pragma unroll
      for (int i = 0; i < 4; i++) {
        int f = i * 256 + t;
        int row = f >> 4, c8 = (f & 15) * 8;
        int yg = ybase - 1 + row;
        uint4 v = make_uint4(0u, 0u, 0u, 0u);
        if (yg >= 0 && yg < N)
          v = *(const uint4*)(xT + ((size_t)b * N + yg) * CD + c8);
        *(uint4*)&Bs[row * 136 + c8] = v;
      }
    }
    __syncthreads();

    floatx4 acc[4][4];
#pragma unroll
    for (int mt = 0; mt < 4; mt++)
#pragma unroll
      for (int nt = 0; nt < 4; nt++) acc[mt][nt] = (floatx4){0.f, 0.f, 0.f, 0.f};

#pragma unroll
    for (int ks = 0; ks < 4; ks++) {
      bf16x8 bb[4];
#pragma unroll
      for (int nt = 0; nt < 4; nt++)
        bb[nt] = *(const bf16x8*)&Bs[(nt * 16 + lm) * 136 + ks * 32 + quad * 8];
#pragma unroll
      for (int mt = 0; mt < 4; mt++)
#pragma unroll
        for (int nt = 0; nt < 4; nt++)
          acc[mt][nt] = MFMA16(wa[mt][ks], bb[nt], acc[mt][nt]);
    }
    __syncthreads();   // all waves done reading Bs before pres2 (alias) writes

    // in-register dw: post[p] = w0*g[p] + w1*g[p+1] + w2*g[p+2] + sb
    const int i1 = (l & 48) | ((lm + 1) & 15);
    const int i2 = (l & 48) | ((lm + 2) & 15);
#pragma unroll
    for (int mt = 0; mt < 4; mt++) {
#pragma unroll
      for (int r = 0; r < 4; r++) {
        int o = wv * 64 + mt * 16 + quad * 4 + r;
        float4 wq = dwq2[o];
        float cc0 = 0.f, cc2 = 0.f;
        if (yw == 0)  cc0 = c0a[o];
        if (yw == 66) cc2 = c2a[o];
        float vv[5], r1[5], r2[5];
#pragma unroll
        for (int nt = 0; nt < 4; nt++) vv[nt] = acc[mt][nt][r];
        vv[4] = 0.f;
#pragma unroll
        for (int nt = 0; nt < 4; nt++) {
          r1[nt] = __shfl(vv[nt], i1);
          r2[nt] = __shfl(vv[nt], i2);
        }
        r1[4] = 0.f; r2[4] = 0.f;
#pragma unroll
        for (int nt = 0; nt < 4; nt++) {
          int p = nt * 16 + lm;
          int y = ybase + p;
          float g1 = (lm == 15) ? r1[nt + 1] : r1[nt];
          float g2 = (lm >= 14) ? r2[nt + 1] : r2[nt];
          float val = wq.x * vv[nt] + wq.y * g1 + wq.z * g2 + wq.w;
          if (y == 0)     val -= cc0;
          if (y == N - 1) val -= cc2;
          bool ok = (p < 62) && (y < N);
          pres2[o * 68 + p] = f2b(ok ? val : 0.f);
        }
      }
    }
    __syncthreads();

    // Gram: wave = head. QK^T 32x32 + q/k norm diagonals over K=64.
    const int h = wv;
    const unsigned short* pq = pres2 + (size_t)(h * 32) * 68;
    const unsigned short* pk = pres2 + (size_t)(128 + h * 32) * 68;
    floatx4 gqk[2][2], gqq[2], gkk[2];
#pragma unroll
    for (int a = 0; a < 2; a++) {
      gqq[a] = (floatx4){0.f, 0.f, 0.f, 0.f};
      gkk[a] = (floatx4){0.f, 0.f, 0.f, 0.f};
#pragma unroll
      for (int c = 0; c < 2; c++) gqk[a][c] = (floatx4){0.f, 0.f, 0.f, 0.f};
    }
#pragma unroll
    for (int kc = 0; kc < 2; kc++) {
      bf16x8 qf[2], kf[2];
#pragma unroll
      for (int tt = 0; tt < 2; tt++) {
        qf[tt] = *(const bf16x8*)&pq[(tt * 16 + lm) * 68 + kc * 32 + quad * 8];
        kf[tt] = *(const bf16x8*)&pk[(tt * 16 + lm) * 68 + kc * 32 + quad * 8];
      }
#pragma unroll
      for (int tq = 0; tq < 2; tq++)
#pragma unroll
        for (int tk = 0; tk < 2; tk++)
          gqk[tq][tk] = MFMA16(qf[tq], kf[tk], gqk[tq][tk]);
      gqq[0] = MFMA16(qf[0], qf[0], gqq[0]);
      gqq[1] = MFMA16(qf[1], qf[1], gqq[1]);
      gkk[0] = MFMA16(kf[0], kf[0], gkk[0]);
      gkk[1] = MFMA16(kf[1], kf[1], gkk[1]);
    }
    float* pp = part2 + ((size_t)b * H_ + h) * 1088;
#pragma unroll
    for (int tq = 0; tq < 2; tq++)
#pragma unroll
      for (int tk = 0; tk < 2; tk++)
#pragma unroll
        for (int r = 0; r < 4; r++)
          atomicAdd(&pp[(tq * 16 + quad * 4 + r) * 32 + tk * 16 + lm],
                    gqk[tq][tk][r]);
    if (quad == (lm >> 2)) {
      int r = lm & 3;
      atomicAdd(&pp[1024 + lm],      gqq[0][r]);
      atomicAdd(&pp[1024 + 16 + lm], gqq[1][r]);
      atomicAdd(&pp[1056 + lm],      gkk[0][r]);
      atomicAdd(&pp[1056 + 16 + lm], gkk[1][r]);
    }
  } else {
    // ==================== v block (proven path) ====================
    unsigned short* Bs   = (unsigned short*)smem;   // [128][136]
    unsigned short* pres = (unsigned short*)smem;   // [i][o] stride 132 (alias)
    const int ytile = blockIdx.x - 67;
    const int obase = 256;
    const int ybase = ytile * 124;
    const bool interior = (ytile >= 1 && ytile <= 32);

    const unsigned short* wbase =
        qkv_wb + (size_t)(obase + wv * 32 + lm) * CD + quad * 8;
    bf16x8 wa0[4], wa1[4];
#pragma unroll
    for (int ks = 0; ks < 4; ks++) {
      wa0[ks] = *(const bf16x8*)(wbase + ks * 32);
      wa1[ks] = *(const bf16x8*)(wbase + 16 * CD + ks * 32);
    }

    if (interior) {
#pragma unroll
      for (int i = 0; i < 8; i++) {
        int f = i * 256 + t;
        int row = f >> 4, c8 = (f & 15) * 8;
        *(uint4*)&Bs[row * 136 + c8] =
            *(const uint4*)(xT + ((size_t)b * N + ybase - 2 + row) * CD + c8);
      }
    } else {
#pragma unroll
      for (int i = 0; i < 8; i++) {
        int f = i * 256 + t;
        int row = f >> 4, c8 = (f & 15) * 8;
        int yg = ybase - 2 + row;
        uint4 v = make_uint4(0u, 0u, 0u, 0u);
        if (yg >= 0 && yg < N)
          v = *(const uint4*)(xT + ((size_t)b * N + yg) * CD + c8);
        *(uint4*)&Bs[row * 136 + c8] = v;
      }
    }
    __syncthreads();

    floatx4 acc[2][8];
#pragma unroll
    for (int mt = 0; mt < 2; mt++)
#pragma unroll
      for (int nt = 0; nt < 8; nt++) acc[mt][nt] = (floatx4){0.f, 0.f, 0.f, 0.f};

#pragma unroll
    for (int ks = 0; ks < 4; ks++) {
#pragma unroll
      for (int nt = 0; nt < 8; nt++) {
        bf16x8 bb = *(const bf16x8*)&Bs[(nt * 16 + lm) * 136 + ks * 32 + quad * 8];
        acc[0][nt] = MFMA16(wa0[ks], bb, acc[0][nt]);
        acc[1][nt] = MFMA16(wa1[ks], bb, acc[1][nt]);
      }
    }

    const int op = t & 63, quarter = t >> 6;
    const int o0 = 2 * op;
    const float4 wqa = dwq[256 + o0];
    const float4 wqb = dwq[256 + o0 + 1];
    __syncthreads();
    if (interior) {
#pragma unroll
      for (int mt = 0; mt < 2; mt++)
#pragma unroll
        for (int r = 0; r < 4; r++) {
          int o2 = wv * 32 + mt * 16 + quad * 4 + r;
          float bias = qkv_b[obase + o2];
#pragma unroll
          for (int nt = 0; nt < 8; nt++) {
            int i = nt * 16 + lm;
            pres[i * 132 + o2] = f2b(acc[mt][nt][r] + bias);
          }
        }
    } else {
#pragma unroll
      for (int mt = 0; mt < 2; mt++)
#pragma unroll
        for (int r = 0; r < 4; r++) {
          int o2 = wv * 32 + mt * 16 + quad * 4 + r;
          float bias = qkv_b[obase + o2];
#pragma unroll
          for (int nt = 0; nt < 8; nt++) {
            int i = nt * 16 + lm;
            int yg = ybase - 2 + i;
            pres[i * 132 + o2] =
                f2b((yg >= 0 && yg < N) ? (acc[mt][nt][r] + bias) : 0.f);
          }
        }
    }
    __syncthreads();
    const unsigned int* pu = (const unsigned int*)pres;   // [i][o-pair]
    int i0 = 2 + quarter * 31;
    unsigned int pm = pu[(i0 - 1) * 66 + op];
    unsigned int pc = pu[i0 * 66 + op];
    if (interior) {
      for (int i = i0; i < i0 + 31; i++) {
        unsigned int pp2 = pu[(i + 1) * 66 + op];
        int yo = ybase - 2 + i;
        float a0 = wqa.x * b2f(pm) + wqa.y * b2f(pc) + wqa.z * b2f(pp2) + wqa.w;
        float a1 = wqb.x * b2fh(pm) + wqb.y * b2fh(pc) + wqb.z * b2fh(pp2) + wqb.w;
        unsigned int pk2 = (unsigned int)f2b(a0) | ((unsigned int)f2b(a1) << 16);
        *(unsigned int*)(vT + ((size_t)b * N + yo) * CD + o0) = pk2;
        pm = pc; pc = pp2;
      }
    } else {
      for (int i = i0; i < i0 + 31; i++) {
        unsigned int pp2 = pu[(i + 1) * 66 + op];
        int yo = ybase - 2 + i;
        if (yo >= 0 && yo < N) {
          float a0 = wqa.x * b2f(pm) + wqa.y * b2f(pc) + wqa.z * b2f(pp2) + wqa.w;
          float a1 = wqb.x * b2fh(pm) + wqb.y * b2fh(pc) + wqb.z * b2fh(pp2) + wqb.w;
          unsigned int pk2 = (unsigned int)f2b(a0) | ((unsigned int)f2b(a1) << 16);
          *(unsigned int*)(vT + ((size_t)b * N + yo) * CD + o0) = pk2;
        }
        pm = pc; pc = pp2;
      }
    }
  }
}

// ---------------------------------------------------------------------------
// K45: read fully-reduced Gram part2[b][h][1088], normalize+temperature,
// exact stable top-k ranks, fold 4 masked softmaxes -> AwtT bf16;
// M = proj_w @ blockdiag(A) via MFMA. grid (B), 256 thr.
// ---------------------------------------------------------------------------
__global__ __launch_bounds__(256) void k45(
    const float* __restrict__ part2, const unsigned short* __restrict__ proj_wb,
    const float* __restrict__ temperature, const float* __restrict__ attn_w,
    unsigned short* __restrict__ Mb)
{
  __shared__ float La[H_][C_][33];
  __shared__ float sq2[256];
  __shared__ float rn[256];
  __shared__ float exL[H_][C_][33];
  __shared__ unsigned char rkL[H_][C_][C_];
  __shared__ unsigned short AwtT[H_][C_][40];
  const int b = blockIdx.x, t = threadIdx.x;

  const float* pbb = part2 + (size_t)b * H_ * 1088;
#pragma unroll
  for (int h = 0; h < H_; h++)
    for (int idx = t; idx < 1088; idx += 256) {
      float s = pbb[h * 1088 + idx];
      if (idx < 1024) La[h][idx >> 5][idx & 31] = s;
      else if (idx < 1056) sq2[h * 32 + (idx - 1024)] = s;
      else sq2[128 + h * 32 + (idx - 1056)] = s;
    }
  __syncthreads();
  rn[t] = 1.f / fmaxf(sqrtf(sq2[t]), 1e-12f);
  __syncthreads();
  for (int e = t; e < 4096; e += 256) {
    int h = e >> 10, i = (e >> 5) & 31, j = e & 31;
    La[h][i][j] *= rn[h * 32 + i] * rn[128 + h * 32 + j] * temperature[h];
  }
  __syncthreads();

  if (t < 128) {
    int h = t >> 5, i = t & 31;
    float m = -1e30f;
    for (int j = 0; j < 32; j++) m = fmaxf(m, La[h][i][j]);
    float S0 = 0.f, S1 = 0.f, S2 = 0.f, S3 = 0.f;
    for (int j = 0; j < 32; j++) {
      float vj = La[h][i][j];
      int r = 0;
      for (int j2 = 0; j2 < 32; j2++) {
        float v2 = La[h][i][j2];
        r += (v2 > vj) || (v2 == vj && j2 < j);
      }
      float e = __expf(vj - m);
      exL[h][i][j] = e;
      rkL[h][i][j] = (unsigned char)r;
      if (r < 16) S0 += e;
      if (r < 21) S1 += e;
      if (r < 24) S2 += e;
      if (r < 25) S3 += e;
    }
    float w0 = attn_w[0] / S0, w1 = attn_w[1] / S1;
    float w2 = attn_w[2] / S2, w3 = attn_w[3] / S3;
    for (int j = 0; j < 32; j++) {
      int r = rkL[h][i][j];
      float cmb = (r < 16 ? w0 : 0.f) + (r < 21 ? w1 : 0.f) +
                  (r < 24 ? w2 : 0.f) + (r < 25 ? w3 : 0.f);
      AwtT[h][j][i] = f2b(exL[h][i][j] * cmb);
    }
  }
  __syncthreads();

  {
    const int wv = t >> 6, l = t & 63, quad = l >> 4, lm = l & 15;
    const int h = wv;
    bf16x8 bfr[2];
#pragma unroll
    for (int jt = 0; jt < 2; jt++)
      bfr[jt] = *(const bf16x8*)&AwtT[h][jt * 16 + lm][quad * 8];
#pragma unroll
    for (int mt = 0; mt < 8; mt++) {
      bf16x8 a = *(const bf16x8*)(proj_wb +
                    (size_t)(mt * 16 + lm) * CD + h * C_ + quad * 8);
#pragma unroll
      for (int jt = 0; jt < 2; jt++) {
        floatx4 acc = (floatx4){0.f, 0.f, 0.f, 0.f};
        acc = MFMA16(a, bfr[jt], acc);
#pragma unroll
        for (int r = 0; r < 4; r++) {
          int row = quad * 4 + r;
          Mb[(size_t)b * 16384 + (mt * 16 + row) * CD + h * C_ + jt * 16 + lm] =
              f2b(acc[r]);
        }
      }
    }
  }
}

// ---------------------------------------------------------------------------
// K6: out[b] = Mb @ V^T + proj_b. A (Mb) per-ks from global (L2-hot);
// LDS = Bs only -> 4 blocks/CU. grid (32, 32), 256 thr.
// ---------------------------------------------------------------------------
__global__ __launch_bounds__(256, 4) void k6_out(
    const unsigned short* __restrict__ vT, const unsigned short* __restrict__ Mb,
    const float* __restrict__ proj_b, float* __restrict__ out)
{
  __shared__ unsigned short Bs[128 * 136];
  const int t = threadIdx.x;
  const int y0 = blockIdx.x * 128, b = blockIdx.y;
  const int wv = t >> 6, l = t & 63, quad = l >> 4, lm = l & 15;

#pragma unroll
  for (int i = 0; i < 8; i++) {
    int f = i * 256 + t;
    int row = f >> 4, c8 = (f & 15) * 8;
    *(uint4*)&Bs[row * 136 + c8] =
        *(const uint4*)(vT + ((size_t)b * N + y0 + row) * CD + c8);
  }
  __syncthreads();

  floatx4 acc[2][8];
#pragma unroll
  for (int mt = 0; mt < 2; mt++)
#pragma unroll
    for (int nt = 0; nt < 8; nt++) acc[mt][nt] = (floatx4){0.f, 0.f, 0.f, 0.f};

  const unsigned short* mbase =
      Mb + (size_t)b * 16384 + (size_t)(wv * 32 + lm) * CD + quad * 8;
#pragma unroll
  for (int ks = 0; ks < 4; ks++) {
    bf16x8 a0 = *(const bf16x8*)(mbase + ks * 32);
    bf16x8 a1 = *(const bf16x8*)(mbase + 16 * CD + ks * 32);
#pragma unroll
    for (int nt = 0; nt < 8; nt++) {
      bf16x8 bb = *(const bf16x8*)&Bs[(nt * 16 + lm) * 136 + ks * 32 + quad * 8];
      acc[0][nt] = MFMA16(a0, bb, acc[0][nt]);
      acc[1][nt] = MFMA16(a1, bb, acc[1][nt]);
    }
  }

#pragma unroll
  for (int mt = 0; mt < 2; mt++)
#pragma unroll
    for (int r = 0; r < 4; r++) {
      int o = wv * 32 + mt * 16 + quad * 4 + r;
      float pb = proj_b[o];
#pragma unroll
      for (int nt = 0; nt < 8; nt++) {
        int y = y0 + nt * 16 + lm;
        out[((size_t)b * CD + o) * N + y] = acc[mt][nt][r] + pb;
      }
    }
}

extern "C" void kernel_launch(void* const* d_in, const int* in_sizes, int n_in,
                              void* d_out, int out_size, void* d_ws, size_t ws_size,
                              hipStream_t stream)
{
  (void)in_sizes; (void)n_in; (void)out_size; (void)ws_size;
  const float* x           = (const float*)d_in[0];
  const float* qkv_w       = (const float*)d_in[1];
  const float* qkv_b       = (const float*)d_in[2];
  const float* dw_w        = (const float*)d_in[3];
  const float* dw_b        = (const float*)d_in[4];
  const float* proj_w      = (const float*)d_in[5];
  const float* proj_b      = (const float*)d_in[6];
  const float* temperature = (const float*)d_in[7];
  const float* attn_w      = (const float*)d_in[8];
  float* out = (float*)d_out;

  unsigned short* xT      = (unsigned short*)d_ws;   // 16,777,216 sh
  unsigned short* qkv_wb  = xT + (size_t)16777216;   //     49,152
  unsigned short* proj_wb = qkv_wb + 49152;          //     16,384
  unsigned short* hole    = proj_wb + 16384;         // (old qkvd slot, unused)
  unsigned short* vT      = hole + (size_t)33554432; // 16,777,216
  unsigned short* Mb      = vT + (size_t)16777216;   //    524,288
  float* part2 = (float*)(Mb + 524288);              //    139,264 f (557 KB)
  // Coefficient tables alias Mb (written k0, read k1, dead before k45's Mb):
  float4* dwq  = (float4*)Mb;                        // 384 f4
  float4* dwq2 = (float4*)(Mb + 3072);               // 256 f4
  float*  c0a  = (float*)(Mb + 5120);                // 256 f
  float*  c2a  = (float*)(Mb + 5632);                // 256 f

  k0_xt    <<<dim3(64, 4, 32), 256, 0, stream>>>(x, xT, qkv_w, proj_w, dw_w,
                                                 dw_b, qkv_b, qkv_wb, proj_wb,
                                                 dwq, dwq2, c0a, c2a, part2);
  k1_qkv_dw<<<dim3(101, 32),   256, 0, stream>>>(xT, qkv_wb, qkv_b, dwq, dwq2,
                                                 c0a, c2a, vT, part2);
  k45      <<<dim3(B_),        256, 0, stream>>>(part2, proj_wb, temperature,
                                                 attn_w, Mb);
  k6_out   <<<dim3(32, B_),    256, 0, stream>>>(vT, Mb, proj_b, out);
}